// Round 3
// baseline (335.750 us; speedup 1.0000x reference)
//
#include <hip/hip_runtime.h>
#include <hip/hip_bf16.h>

// B=4, S=2048, E=1024, H=16, D=64
#define PB 4
#define PS 2048
#define PH 16
#define PD 64
#define PE 1024

typedef short v8s __attribute__((ext_vector_type(8)));
typedef float v4f __attribute__((ext_vector_type(4)));

// Q pre-scale: 1/sqrt(D) * log2(e), so softmax exp() becomes exp2()
#define QSCALE 0.18033688f

__device__ __forceinline__ ushort f2b(float f) {
  union { __hip_bfloat16 b; ushort u; } cv;
  cv.b = __float2bfloat16(f);
  return cv.u;
}

#if __has_builtin(__builtin_amdgcn_exp2f)
__device__ __forceinline__ float fexp2(float x) { return __builtin_amdgcn_exp2f(x); }
#else
__device__ __forceinline__ float fexp2(float x) { return exp2f(x); }
#endif

// async 16B global->LDS (direct DMA, no VGPR round trip)
__device__ __forceinline__ void cp16(const __hip_bfloat16* g, __hip_bfloat16* l) {
  __builtin_amdgcn_global_load_lds(
      (const __attribute__((address_space(1))) void*)g,
      (__attribute__((address_space(3))) void*)l, 16, 0, 0);
}

// raw barrier with compiler memory fences on both sides
__device__ __forceinline__ void barrier_fence() {
  asm volatile("" ::: "memory");
  __builtin_amdgcn_s_barrier();
  asm volatile("" ::: "memory");
}

// ---------------------------------------------------------------------------
// Prep kernels: fp32 -> bf16 convert / transpose (memory-bound)
// ---------------------------------------------------------------------------
__global__ __launch_bounds__(256) void conv_f2b(const float* __restrict__ S,
                                                __hip_bfloat16* __restrict__ D) {
  int i = blockIdx.x * 256 + threadIdx.x;
  float4 f = reinterpret_cast<const float4*>(S)[i];
  union { ushort u[4]; uint2 v; } pk;
  pk.u[0] = f2b(f.x); pk.u[1] = f2b(f.y); pk.u[2] = f2b(f.z); pk.u[3] = f2b(f.w);
  reinterpret_cast<uint2*>(D)[i] = pk.v;
}

// S [R][C] fp32 -> D [C][R] bf16
__global__ __launch_bounds__(256) void transp_f2b(const float* __restrict__ S,
                                                  __hip_bfloat16* __restrict__ D,
                                                  int R, int C) {
  __shared__ float tile[32][33];
  const int t = threadIdx.x;
  const int tx = t & 31, ty = t >> 5;
  const int r0 = blockIdx.y * 32, c0 = blockIdx.x * 32;
#pragma unroll
  for (int i = 0; i < 4; ++i)
    tile[ty + 8 * i][tx] = S[(size_t)(r0 + ty + 8 * i) * C + c0 + tx];
  __syncthreads();
#pragma unroll
  for (int i = 0; i < 4; ++i)
    D[(size_t)(c0 + ty + 8 * i) * R + r0 + tx] = __float2bfloat16(tile[tx][ty + 8 * i]);
}

// ---------------------------------------------------------------------------
// MFMA GEMM, BK=64, XOR-swizzled LDS, global_load_lds width-16 staging.
// 128x128 tile, 4 waves x (64x64). MODE 0: QKV scatter; MODE 1: proj fp32.
// ---------------------------------------------------------------------------
template <int MODE>
__global__ __launch_bounds__(256) void gemm_bt(
    const __hip_bfloat16* __restrict__ A, const __hip_bfloat16* __restrict__ BT,
    const float* __restrict__ bias, void* __restrict__ outv) {
  __shared__ __hip_bfloat16 As[128 * 64];
  __shared__ __hip_bfloat16 Bs[128 * 64];
  const int t = threadIdx.x;
  const int lane = t & 63, w = t >> 6;
  const int ln = lane & 15, qd = lane >> 4;
  const int wm = w >> 1, wn = w & 1;
  const int m0 = blockIdx.y * 128, n0 = blockIdx.x * 128;
  v4f acc[4][4] = {};

  for (int k0 = 0; k0 < PE; k0 += 64) {
    __syncthreads();
#pragma unroll
    for (int i = 0; i < 4; ++i) {
      int idx = t + 256 * i;           // 0..1023 16B slots
      int r = idx >> 3, cs = idx & 7;  // 8 chunks per 64-elem row
      int cg = cs ^ (r & 7);
      cp16(A + (size_t)(m0 + r) * PE + k0 + cg * 8, As + idx * 8);
      cp16(BT + (size_t)(n0 + r) * PE + k0 + cg * 8, Bs + idx * 8);
    }
    __syncthreads();
#pragma unroll
    for (int kk = 0; kk < 2; ++kk) {
      v8s af[4], bf[4];
#pragma unroll
      for (int mb = 0; mb < 4; ++mb) {
        int ra = wm * 64 + mb * 16 + ln;
        int ca = (kk * 4 + qd) ^ (ra & 7);
        af[mb] = *reinterpret_cast<const v8s*>(As + ra * 64 + ca * 8);
      }
#pragma unroll
      for (int nb = 0; nb < 4; ++nb) {
        int rb = wn * 64 + nb * 16 + ln;
        int cb = (kk * 4 + qd) ^ (rb & 7);
        bf[nb] = *reinterpret_cast<const v8s*>(Bs + rb * 64 + cb * 8);
      }
#pragma unroll
      for (int mb = 0; mb < 4; ++mb)
#pragma unroll
        for (int nb = 0; nb < 4; ++nb)
          acc[mb][nb] = __builtin_amdgcn_mfma_f32_16x16x32_bf16(af[mb], bf[nb],
                                                                acc[mb][nb], 0, 0, 0);
    }
  }

  const int mwb = m0 + wm * 64 + qd * 4;
  const int nwb = n0 + wn * 64 + ln;
  if (MODE == 0) {
    __hip_bfloat16* QKV = (__hip_bfloat16*)outv;
#pragma unroll
    for (int nb = 0; nb < 4; ++nb) {
      int n = nwb + nb * 16;
      float bv = bias[n];
      int which = n >> 10, h = (n >> 6) & 15, d = n & 63;
#pragma unroll
      for (int mb = 0; mb < 4; ++mb) {
        int r0 = mwb + mb * 16;
        int b = r0 >> 11, s0 = r0 & (PS - 1);
        v4f a = acc[mb][nb];
        if (which == 2) {
          union { ushort u[4]; uint2 v; } pk;
#pragma unroll
          for (int i = 0; i < 4; ++i) pk.u[i] = f2b(a[i] + bv);
          size_t idx = (((size_t)(2 * PB + b) * PH + h) * PD + d) * PS + s0;
          *reinterpret_cast<uint2*>(&QKV[idx]) = pk.v;
        } else {
          float sc = (which == 0) ? QSCALE : 1.0f;
          size_t base = (((size_t)(which * PB + b) * PH + h) * PS + s0) * PD + d;
#pragma unroll
          for (int i = 0; i < 4; ++i)
            QKV[base + (size_t)i * PD] = __float2bfloat16((a[i] + bv) * sc);
        }
      }
    }
  } else {
    float* Co = (float*)outv;
#pragma unroll
    for (int nb = 0; nb < 4; ++nb) {
      int n = nwb + nb * 16;
      float bv = bias[n];
#pragma unroll
      for (int mb = 0; mb < 4; ++mb) {
        int r0 = mwb + mb * 16;
        v4f a = acc[mb][nb];
#pragma unroll
        for (int i = 0; i < 4; ++i)
          Co[(size_t)(r0 + i) * PE + n] = a[i] + bv;
      }
    }
  }
}

// ---------------------------------------------------------------------------
// MFMA flash attention v6: register-resident P (v4) + 2-phase pipeline
// UNDER THE OCCUPANCY CLIFFS (R2 lesson: v5's 64KB LDS + 132 VGPR halved
// occupancy and lost). 64-key tiles: K 8KB + Vt 8KB per buffer, x2 = 32KB
// total (same as v4). Prefetch tile t+1 issued before compute(t), counted
// vmcnt(4) keeps it in flight across the acquire barrier; 2 barriers/tile
// (WAR release + RAW acquire). __launch_bounds__(256,4) caps VGPR at 128
// so 4 blocks/CU are retained.
// QKV bf16: Q/K [b,h,s,d], V [b,h,d,s]. O bf16 [b,s,h,d]. Q pre-scaled.
// ---------------------------------------------------------------------------
__global__ __launch_bounds__(256, 4) void attn_mfma6(
    const __hip_bfloat16* __restrict__ QKV, __hip_bfloat16* __restrict__ O) {
  __shared__ __hip_bfloat16 Ks[2][64 * 64];   // [key][d], XOR-swizzled chunks
  __shared__ __hip_bfloat16 Vts[2][64 * 64];  // [d][key], XOR-swizzled chunks
  const int t = threadIdx.x;
  const int lane = t & 63, w = t >> 6;
  const int ln = lane & 15, qd = lane >> 4;
  const int b = blockIdx.y >> 4, h = blockIdx.y & 15;
  const int q0 = blockIdx.x * 128;
  const __hip_bfloat16* Qb = QKV + (size_t)(b * PH + h) * PS * PD;
  const __hip_bfloat16* Kb = QKV + (size_t)((PB + b) * PH + h) * PS * PD;
  const __hip_bfloat16* Vb = QKV + (size_t)((2 * PB + b) * PH + h) * PD * PS;

  // Q B-frags: wave w owns q-rows q0+32w .. +31 (two 16-row sub-blocks u)
  v8s qf[2][2];
#pragma unroll
  for (int u = 0; u < 2; ++u) {
    size_t qr = (size_t)(q0 + 32 * w + 16 * u + ln) * PD;
    qf[u][0] = *reinterpret_cast<const v8s*>(Qb + qr + qd * 8);
    qf[u][1] = *reinterpret_cast<const v8s*>(Qb + qr + 32 + qd * 8);
  }
  v4f oacc[2][4] = {};
  float lrow[2] = {0.f, 0.f};

  // kt-invariant LDS read address components
  const int r7 = ln & 7;
  const int c0 = qd ^ r7;  // K 16B-slot base (second read: c0^4)
  const int q1 = qd & 1, qh = qd >> 1;
  int soff[2][2];  // V 8B-slot offsets per k-slice s (uint2 units)
#pragma unroll
  for (int s = 0; s < 2; ++s) {
    int L0 = 4 * s + qh;
    soff[s][0] = (((L0 ^ r7) << 1) | q1);
    soff[s][1] = ((((L0 + 2) ^ r7) << 1) | q1);
  }
  int rvoff[4];  // V row offsets (uint2 units; row = 64 bf16 = 16 uint2)
#pragma unroll
  for (int db = 0; db < 4; ++db) rvoff[db] = (db * 16 + ln) * 16;

  // 64-key tile staging: 512 16B-slots each for K and Vt -> 4 cp16/thread
  auto STAGE = [&](int buf, int kt) {
#pragma unroll
    for (int i = 0; i < 2; ++i) {
      int idx = t + 256 * i;  // 0..511 16B slots
      int rk = idx >> 3, ck = (idx & 7) ^ (rk & 7);
      cp16(Kb + (size_t)(kt + rk) * PD + ck * 8, Ks[buf] + idx * 8);
      int rv = idx >> 3, cv = (idx & 7) ^ (rv & 7);
      cp16(Vb + (size_t)rv * PS + kt + cv * 8, Vts[buf] + idx * 8);
    }
  };

  auto COMPUTE = [&](int buf) {
    const __hip_bfloat16* Kbuf = Ks[buf];
    const uint2* Vbuf = reinterpret_cast<const uint2*>(Vts[buf]);
    // S^T = K Q^T per sub-block; exp2; pack P into registers (pw)
    uint2 pw[2][4];
#pragma unroll
    for (int u = 0; u < 2; ++u) {
      float psum = 0.f;
#pragma unroll
      for (int nb = 0; nb < 4; ++nb) {
        const __hip_bfloat16* kr = Kbuf + (nb * 16 + ln) * 64;
        v8s k0 = *reinterpret_cast<const v8s*>(kr + c0 * 8);
        v8s k1 = *reinterpret_cast<const v8s*>(kr + (c0 ^ 4) * 8);
        v4f z = {};
        z = __builtin_amdgcn_mfma_f32_16x16x32_bf16(k0, qf[u][0], z, 0, 0, 0);
        v4f sv = __builtin_amdgcn_mfma_f32_16x16x32_bf16(k1, qf[u][1], z, 0, 0, 0);
        // lane holds keys nb*16+qd*4+i of q = 32w+16u+ln
        union { ushort pu[4]; uint2 pv; } pk;
#pragma unroll
        for (int i = 0; i < 4; ++i) {
          float p = fexp2(sv[i]);
          psum += p;
          pk.pu[i] = f2b(p);
        }
        pw[u][nb] = pk.pv;
      }
      // reduce over qd lane-groups (lane bits 4,5)
      psum += __shfl_xor(psum, 16);
      psum += __shfl_xor(psum, 32);
      lrow[u] += psum;
    }
    // O += P V, P direct from registers with permuted key order.
    // Slice s covers keys [32s,32s+32): A = concat(pw[2s], pw[2s+1]);
    // k-slot qd*8+j <-> key (2s+(j>>2))*16 + qd*4 + (j&3), matched on V.
#pragma unroll
    for (int s = 0; s < 2; ++s) {
      union { v8s v; uint2 u2[2]; } a0, a1;
      a0.u2[0] = pw[0][2 * s]; a0.u2[1] = pw[0][2 * s + 1];
      a1.u2[0] = pw[1][2 * s]; a1.u2[1] = pw[1][2 * s + 1];
      __builtin_amdgcn_s_setprio(1);
#pragma unroll
      for (int db = 0; db < 4; ++db) {
        union { v8s v; uint2 u2[2]; } vf;
        vf.u2[0] = Vbuf[rvoff[db] + soff[s][0]];
        vf.u2[1] = Vbuf[rvoff[db] + soff[s][1]];
        oacc[0][db] = __builtin_amdgcn_mfma_f32_16x16x32_bf16(a0.v, vf.v,
                                                              oacc[0][db], 0, 0, 0);
        oacc[1][db] = __builtin_amdgcn_mfma_f32_16x16x32_bf16(a1.v, vf.v,
                                                              oacc[1][db], 0, 0, 0);
      }
      __builtin_amdgcn_s_setprio(0);
    }
  };

  // 2-phase pipeline, 2 barriers/tile:
  //   STAGE(next) ; vmcnt(4) [tile t landed, next stays in flight] ;
  //   barrier(acquire) ; COMPUTE(t) ; barrier(release: reads done before
  //   anyone overwrites this buffer next iteration)
  STAGE(0, 0);
#pragma unroll 1
  for (int it = 0; it < PS / 64; it += 2) {
    STAGE(1, (it + 1) * 64);
    asm volatile("s_waitcnt vmcnt(4)" ::: "memory");
    barrier_fence();
    COMPUTE(0);
    barrier_fence();
    if (it + 2 < PS / 64) {
      STAGE(0, (it + 2) * 64);
      asm volatile("s_waitcnt vmcnt(4)" ::: "memory");
    } else {
      asm volatile("s_waitcnt vmcnt(0)" ::: "memory");
    }
    barrier_fence();
    COMPUTE(1);
    barrier_fence();
  }

  // epilogue: redistribute lrow (indexed by q=ln) to O C-layout (q=qd*4+i)
#pragma unroll
  for (int u = 0; u < 2; ++u) {
#pragma unroll
    for (int i = 0; i < 4; ++i) {
      float inv = 1.f / __shfl(lrow[u], qd * 4 + i);
      int sg = q0 + 32 * w + 16 * u + qd * 4 + i;
      size_t base = (((size_t)b * PS + sg) * PH + h) * PD;
#pragma unroll
      for (int db = 0; db < 4; ++db)
        O[base + db * 16 + ln] = __float2bfloat16(oacc[u][db][i] * inv);
    }
  }
}

// ---------------------------------------------------------------------------
// Legacy fp32-input GEMM (small-ws fallback)
// ---------------------------------------------------------------------------
__device__ __forceinline__ uint2 load4bf(const float* p) {
  const float4 f = *reinterpret_cast<const float4*>(p);
  union { ushort u[4]; uint2 v; } pk;
  pk.u[0] = f2b(f.x); pk.u[1] = f2b(f.y); pk.u[2] = f2b(f.z); pk.u[3] = f2b(f.w);
  return pk.v;
}
__device__ __forceinline__ uint2 load4bf(const __hip_bfloat16* p) {
  return *reinterpret_cast<const uint2*>(p);
}

template <typename AT, int MODE>
__global__ __launch_bounds__(256) void gemm128(
    const AT* __restrict__ A, const float* __restrict__ Bm,
    const float* __restrict__ bias, void* __restrict__ outv, int ldb) {
  __shared__ __hip_bfloat16 As[128][40];
  __shared__ __hip_bfloat16 Bs[128][40];
  const int t = threadIdx.x;
  const int lane = t & 63, w = t >> 6;
  const int ln = lane & 15, qd = lane >> 4;
  const int wm = w >> 1, wn = w & 1;
  const int m0 = blockIdx.y * 128, n0 = blockIdx.x * 128;
  v4f acc[4][4] = {};
  for (int k0 = 0; k0 < PE; k0 += 32) {
    __syncthreads();
#pragma unroll
    for (int i = 0; i < 4; ++i) {
      int p = t + 256 * i;
      int m = p >> 3, kc = p & 7;
      *reinterpret_cast<uint2*>(&As[m][kc * 4]) =
          load4bf(A + (size_t)(m0 + m) * PE + k0 + kc * 4);
    }
#pragma unroll
    for (int i = 0; i < 4; ++i) {
      int p = t + 256 * i;
      int n = p & 127, kc = p >> 7;
      union { ushort u[4]; uint2 v; } pk;
#pragma unroll
      for (int r = 0; r < 4; ++r)
        pk.u[r] = f2b(Bm[(size_t)(k0 + kc * 4 + r) * ldb + n0 + n]);
      *reinterpret_cast<uint2*>(&Bs[n][kc * 4]) = pk.v;
    }
    __syncthreads();
    v8s af[4], bf[4];
#pragma unroll
    for (int mb = 0; mb < 4; ++mb)
      af[mb] = *reinterpret_cast<const v8s*>(&As[wm * 64 + mb * 16 + ln][qd * 8]);
#pragma unroll
    for (int nb = 0; nb < 4; ++nb)
      bf[nb] = *reinterpret_cast<const v8s*>(&Bs[wn * 64 + nb * 16 + ln][qd * 8]);
#pragma unroll
    for (int mb = 0; mb < 4; ++mb)
#pragma unroll
      for (int nb = 0; nb < 4; ++nb)
        acc[mb][nb] = __builtin_amdgcn_mfma_f32_16x16x32_bf16(af[mb], bf[nb],
                                                              acc[mb][nb], 0, 0, 0);
  }
  const int mwb = m0 + wm * 64 + qd * 4;
  const int nwb = n0 + wn * 64 + ln;
  if (MODE == 0) {
    __hip_bfloat16* QKV = (__hip_bfloat16*)outv;
#pragma unroll
    for (int nb = 0; nb < 4; ++nb) {
      int n = nwb + nb * 16;
      float bv = bias[n];
      int which = n >> 10, h = (n >> 6) & 15, d = n & 63;
#pragma unroll
      for (int mb = 0; mb < 4; ++mb) {
        int r0 = mwb + mb * 16;
        int b = r0 >> 11, s0 = r0 & (PS - 1);
        v4f a = acc[mb][nb];
        if (which == 2) {
          union { ushort u[4]; uint2 v; } pk;
#pragma unroll
          for (int i = 0; i < 4; ++i) pk.u[i] = f2b(a[i] + bv);
          size_t idx = (((size_t)(2 * PB + b) * PH + h) * PD + d) * PS + s0;
          *reinterpret_cast<uint2*>(&QKV[idx]) = pk.v;
        } else {
          float sc = (which == 0) ? QSCALE : 1.0f;
          size_t base = (((size_t)(which * PB + b) * PH + h) * PS + s0) * PD + d;
#pragma unroll
          for (int i = 0; i < 4; ++i)
            QKV[base + (size_t)i * PD] = __float2bfloat16((a[i] + bv) * sc);
        }
      }
    }
  } else {
    float* Co = (float*)outv;
#pragma unroll
    for (int nb = 0; nb < 4; ++nb) {
      int n = nwb + nb * 16;
      float bv = bias[n];
#pragma unroll
      for (int mb = 0; mb < 4; ++mb) {
        int r0 = mwb + mb * 16;
        v4f a = acc[mb][nb];
#pragma unroll
        for (int i = 0; i < 4; ++i)
          Co[(size_t)(r0 + i) * PE + n] = a[i] + bv;
      }
    }
  }
}

// ---------------------------------------------------------------------------
extern "C" void kernel_launch(void* const* d_in, const int* in_sizes, int n_in,
                              void* d_out, int out_size, void* d_ws,
                              size_t ws_size, hipStream_t stream) {
  const float* x = (const float*)d_in[0];
  const float* w_qkv = (const float*)d_in[1];
  const float* b_qkv = (const float*)d_in[2];
  const float* w_proj = (const float*)d_in[3];
  const float* b_proj = (const float*)d_in[4];
  float* out = (float*)d_out;

  const size_t xE = (size_t)PB * PS * PE;             // 8,388,608
  const size_t wqE = (size_t)PE * 3 * PE;             // 3,145,728
  const size_t wpE = (size_t)PE * PE;                 // 1,048,576
  const size_t qkvE = (size_t)3 * PB * PH * PS * PD;  // 25,165,824
  const size_t needMain = (xE + wqE + wpE + qkvE) * 2;  // 75,497,472 B

  dim3 blk(256);
  dim3 gq(24, 64), ga(16, 64), gp(8, 64);

  if (ws_size >= needMain) {
    __hip_bfloat16* xb = (__hip_bfloat16*)d_ws;
    __hip_bfloat16* wqkvT = xb + xE;
    __hip_bfloat16* wprojT = wqkvT + wqE;
    __hip_bfloat16* qkv = wprojT + wpE;
    __hip_bfloat16* o = xb;  // xb dead after qkv gemm

    conv_f2b<<<dim3(xE / 1024), blk, 0, stream>>>(x, xb);
    transp_f2b<<<dim3(96, 32), blk, 0, stream>>>(w_qkv, wqkvT, PE, 3 * PE);
    transp_f2b<<<dim3(32, 32), blk, 0, stream>>>(w_proj, wprojT, PE, PE);
    gemm_bt<0><<<gq, blk, 0, stream>>>(xb, wqkvT, b_qkv, qkv);
    attn_mfma6<<<ga, blk, 0, stream>>>(qkv, o);
    gemm_bt<1><<<gp, blk, 0, stream>>>(o, wprojT, b_proj, out);
  } else {
    // legacy small-ws path
    __hip_bfloat16* qkv = (__hip_bfloat16*)d_ws;
    if (ws_size >= (qkvE + xE) * 2) {
      __hip_bfloat16* o = qkv + qkvE;
      gemm128<float, 0><<<gq, blk, 0, stream>>>(x, w_qkv, b_qkv, qkv, 3 * PE);
      attn_mfma6<<<ga, blk, 0, stream>>>(qkv, o);
      gemm128<__hip_bfloat16, 1><<<gp, blk, 0, stream>>>(o, w_proj, b_proj, out, PE);
    } else {
      __hip_bfloat16* o = (__hip_bfloat16*)d_out;
      float* tmp = (float*)d_ws;
      gemm128<float, 0><<<gq, blk, 0, stream>>>(x, w_qkv, b_qkv, qkv, 3 * PE);
      attn_mfma6<<<ga, blk, 0, stream>>>(qkv, o);
      gemm128<__hip_bfloat16, 1><<<gp, blk, 0, stream>>>(o, w_proj, b_proj, tmp, PE);
      hipMemcpyAsync(d_out, tmp, xE * sizeof(float), hipMemcpyDeviceToDevice, stream);
    }
  }
}

// Round 4
// 289.909 us; speedup vs baseline: 1.1581x; 1.1581x over previous
//
#include <hip/hip_runtime.h>
#include <hip/hip_bf16.h>

// B=4, S=2048, E=1024, H=16, D=64
#define PB 4
#define PS 2048
#define PH 16
#define PD 64
#define PE 1024

typedef short v8s __attribute__((ext_vector_type(8)));
typedef float v4f __attribute__((ext_vector_type(4)));

// Q pre-scale: 1/sqrt(D) * log2(e), so softmax exp() becomes exp2()
#define QSCALE 0.18033688f

__device__ __forceinline__ ushort f2b(float f) {
  union { __hip_bfloat16 b; ushort u; } cv;
  cv.b = __float2bfloat16(f);
  return cv.u;
}

#if __has_builtin(__builtin_amdgcn_exp2f)
__device__ __forceinline__ float fexp2(float x) { return __builtin_amdgcn_exp2f(x); }
#else
__device__ __forceinline__ float fexp2(float x) { return exp2f(x); }
#endif

// async 16B global->LDS (direct DMA, no VGPR round trip)
__device__ __forceinline__ void cp16(const __hip_bfloat16* g, __hip_bfloat16* l) {
  __builtin_amdgcn_global_load_lds(
      (const __attribute__((address_space(1))) void*)g,
      (__attribute__((address_space(3))) void*)l, 16, 0, 0);
}

// raw barrier with compiler memory fences on both sides
__device__ __forceinline__ void barrier_fence() {
  asm volatile("" ::: "memory");
  __builtin_amdgcn_s_barrier();
  asm volatile("" ::: "memory");
}

// ---------------------------------------------------------------------------
// Prep kernels: fp32 -> bf16 convert / transpose (memory-bound)
// ---------------------------------------------------------------------------
__global__ __launch_bounds__(256) void conv_f2b(const float* __restrict__ S,
                                                __hip_bfloat16* __restrict__ D) {
  int i = blockIdx.x * 256 + threadIdx.x;
  float4 f = reinterpret_cast<const float4*>(S)[i];
  union { ushort u[4]; uint2 v; } pk;
  pk.u[0] = f2b(f.x); pk.u[1] = f2b(f.y); pk.u[2] = f2b(f.z); pk.u[3] = f2b(f.w);
  reinterpret_cast<uint2*>(D)[i] = pk.v;
}

// S [R][C] fp32 -> D [C][R] bf16
__global__ __launch_bounds__(256) void transp_f2b(const float* __restrict__ S,
                                                  __hip_bfloat16* __restrict__ D,
                                                  int R, int C) {
  __shared__ float tile[32][33];
  const int t = threadIdx.x;
  const int tx = t & 31, ty = t >> 5;
  const int r0 = blockIdx.y * 32, c0 = blockIdx.x * 32;
#pragma unroll
  for (int i = 0; i < 4; ++i)
    tile[ty + 8 * i][tx] = S[(size_t)(r0 + ty + 8 * i) * C + c0 + tx];
  __syncthreads();
#pragma unroll
  for (int i = 0; i < 4; ++i)
    D[(size_t)(c0 + ty + 8 * i) * R + r0 + tx] = __float2bfloat16(tile[tx][ty + 8 * i]);
}

// ---------------------------------------------------------------------------
// MFMA GEMM, BK=64, XOR-swizzled LDS, global_load_lds width-16 staging.
// 128x128 tile, 4 waves x (64x64). MODE 0: QKV scatter; MODE 1: proj fp32.
// ---------------------------------------------------------------------------
template <int MODE>
__global__ __launch_bounds__(256) void gemm_bt(
    const __hip_bfloat16* __restrict__ A, const __hip_bfloat16* __restrict__ BT,
    const float* __restrict__ bias, void* __restrict__ outv) {
  __shared__ __hip_bfloat16 As[128 * 64];
  __shared__ __hip_bfloat16 Bs[128 * 64];
  const int t = threadIdx.x;
  const int lane = t & 63, w = t >> 6;
  const int ln = lane & 15, qd = lane >> 4;
  const int wm = w >> 1, wn = w & 1;
  const int m0 = blockIdx.y * 128, n0 = blockIdx.x * 128;
  v4f acc[4][4] = {};

  for (int k0 = 0; k0 < PE; k0 += 64) {
    __syncthreads();
#pragma unroll
    for (int i = 0; i < 4; ++i) {
      int idx = t + 256 * i;           // 0..1023 16B slots
      int r = idx >> 3, cs = idx & 7;  // 8 chunks per 64-elem row
      int cg = cs ^ (r & 7);
      cp16(A + (size_t)(m0 + r) * PE + k0 + cg * 8, As + idx * 8);
      cp16(BT + (size_t)(n0 + r) * PE + k0 + cg * 8, Bs + idx * 8);
    }
    __syncthreads();
#pragma unroll
    for (int kk = 0; kk < 2; ++kk) {
      v8s af[4], bf[4];
#pragma unroll
      for (int mb = 0; mb < 4; ++mb) {
        int ra = wm * 64 + mb * 16 + ln;
        int ca = (kk * 4 + qd) ^ (ra & 7);
        af[mb] = *reinterpret_cast<const v8s*>(As + ra * 64 + ca * 8);
      }
#pragma unroll
      for (int nb = 0; nb < 4; ++nb) {
        int rb = wn * 64 + nb * 16 + ln;
        int cb = (kk * 4 + qd) ^ (rb & 7);
        bf[nb] = *reinterpret_cast<const v8s*>(Bs + rb * 64 + cb * 8);
      }
#pragma unroll
      for (int mb = 0; mb < 4; ++mb)
#pragma unroll
        for (int nb = 0; nb < 4; ++nb)
          acc[mb][nb] = __builtin_amdgcn_mfma_f32_16x16x32_bf16(af[mb], bf[nb],
                                                                acc[mb][nb], 0, 0, 0);
    }
  }

  const int mwb = m0 + wm * 64 + qd * 4;
  const int nwb = n0 + wn * 64 + ln;
  if (MODE == 0) {
    __hip_bfloat16* QKV = (__hip_bfloat16*)outv;
#pragma unroll
    for (int nb = 0; nb < 4; ++nb) {
      int n = nwb + nb * 16;
      float bv = bias[n];
      int which = n >> 10, h = (n >> 6) & 15, d = n & 63;
#pragma unroll
      for (int mb = 0; mb < 4; ++mb) {
        int r0 = mwb + mb * 16;
        int b = r0 >> 11, s0 = r0 & (PS - 1);
        v4f a = acc[mb][nb];
        if (which == 2) {
          union { ushort u[4]; uint2 v; } pk;
#pragma unroll
          for (int i = 0; i < 4; ++i) pk.u[i] = f2b(a[i] + bv);
          size_t idx = (((size_t)(2 * PB + b) * PH + h) * PD + d) * PS + s0;
          *reinterpret_cast<uint2*>(&QKV[idx]) = pk.v;
        } else {
          float sc = (which == 0) ? QSCALE : 1.0f;
          size_t base = (((size_t)(which * PB + b) * PH + h) * PS + s0) * PD + d;
#pragma unroll
          for (int i = 0; i < 4; ++i)
            QKV[base + (size_t)i * PD] = __float2bfloat16((a[i] + bv) * sc);
        }
      }
    }
  } else {
    float* Co = (float*)outv;
#pragma unroll
    for (int nb = 0; nb < 4; ++nb) {
      int n = nwb + nb * 16;
      float bv = bias[n];
#pragma unroll
      for (int mb = 0; mb < 4; ++mb) {
        int r0 = mwb + mb * 16;
        v4f a = acc[mb][nb];
#pragma unroll
        for (int i = 0; i < 4; ++i)
          Co[(size_t)(r0 + i) * PE + n] = a[i] + bv;
      }
    }
  }
}

// ---------------------------------------------------------------------------
// MFMA flash attention v7: v6's 2-phase pipeline (64-key double-buffered
// tiles, 32KB LDS total, register-resident P, counted vmcnt(4)) with PLAIN
// __launch_bounds__(256). R3 lesson: (256,4) made the allocator pick 64
// VGPR and spill the accumulators to scratch (WRITE_SIZE 16->207MB,
// MfmaUtil 18%). v4 compiled to 112 VGPR spill-free under plain bounds and
// this body is smaller, so expect ~110 VGPR -> 4 waves/SIMD, no scratch.
// QKV bf16: Q/K [b,h,s,d], V [b,h,d,s]. O bf16 [b,s,h,d]. Q pre-scaled.
// ---------------------------------------------------------------------------
__global__ __launch_bounds__(256) void attn_mfma7(
    const __hip_bfloat16* __restrict__ QKV, __hip_bfloat16* __restrict__ O) {
  __shared__ __hip_bfloat16 Ks[2][64 * 64];   // [key][d], XOR-swizzled chunks
  __shared__ __hip_bfloat16 Vts[2][64 * 64];  // [d][key], XOR-swizzled chunks
  const int t = threadIdx.x;
  const int lane = t & 63, w = t >> 6;
  const int ln = lane & 15, qd = lane >> 4;
  const int b = blockIdx.y >> 4, h = blockIdx.y & 15;
  const int q0 = blockIdx.x * 128;
  const __hip_bfloat16* Qb = QKV + (size_t)(b * PH + h) * PS * PD;
  const __hip_bfloat16* Kb = QKV + (size_t)((PB + b) * PH + h) * PS * PD;
  const __hip_bfloat16* Vb = QKV + (size_t)((2 * PB + b) * PH + h) * PD * PS;

  // Q B-frags: wave w owns q-rows q0+32w .. +31 (two 16-row sub-blocks u)
  v8s qf[2][2];
#pragma unroll
  for (int u = 0; u < 2; ++u) {
    size_t qr = (size_t)(q0 + 32 * w + 16 * u + ln) * PD;
    qf[u][0] = *reinterpret_cast<const v8s*>(Qb + qr + qd * 8);
    qf[u][1] = *reinterpret_cast<const v8s*>(Qb + qr + 32 + qd * 8);
  }
  v4f oacc[2][4] = {};
  float lrow[2] = {0.f, 0.f};

  // kt-invariant LDS read address components
  const int r7 = ln & 7;
  const int c0 = qd ^ r7;  // K 16B-slot base (second read: c0^4)
  const int q1 = qd & 1, qh = qd >> 1;
  int soff[2][2];  // V 8B-slot offsets per k-slice s (uint2 units)
#pragma unroll
  for (int s = 0; s < 2; ++s) {
    int L0 = 4 * s + qh;
    soff[s][0] = (((L0 ^ r7) << 1) | q1);
    soff[s][1] = ((((L0 + 2) ^ r7) << 1) | q1);
  }
  int rvoff[4];  // V row offsets (uint2 units; row = 64 bf16 = 16 uint2)
#pragma unroll
  for (int db = 0; db < 4; ++db) rvoff[db] = (db * 16 + ln) * 16;

  // 64-key tile staging: 512 16B-slots each for K and Vt -> 4 cp16/thread
  auto STAGE = [&](int buf, int kt) {
#pragma unroll
    for (int i = 0; i < 2; ++i) {
      int idx = t + 256 * i;  // 0..511 16B slots
      int r = idx >> 3, c = (idx & 7) ^ (r & 7);
      cp16(Kb + (size_t)(kt + r) * PD + c * 8, Ks[buf] + idx * 8);
      cp16(Vb + (size_t)r * PS + kt + c * 8, Vts[buf] + idx * 8);
    }
  };

  auto COMPUTE = [&](int buf) {
    const __hip_bfloat16* Kbuf = Ks[buf];
    const uint2* Vbuf = reinterpret_cast<const uint2*>(Vts[buf]);
    // S^T = K Q^T per sub-block; exp2; pack P into registers (pw)
    uint2 pw[2][4];
#pragma unroll
    for (int u = 0; u < 2; ++u) {
      float psum = 0.f;
#pragma unroll
      for (int nb = 0; nb < 4; ++nb) {
        const __hip_bfloat16* kr = Kbuf + (nb * 16 + ln) * 64;
        v8s k0 = *reinterpret_cast<const v8s*>(kr + c0 * 8);
        v8s k1 = *reinterpret_cast<const v8s*>(kr + (c0 ^ 4) * 8);
        v4f z = {};
        z = __builtin_amdgcn_mfma_f32_16x16x32_bf16(k0, qf[u][0], z, 0, 0, 0);
        v4f sv = __builtin_amdgcn_mfma_f32_16x16x32_bf16(k1, qf[u][1], z, 0, 0, 0);
        // lane holds keys nb*16+qd*4+i of q = 32w+16u+ln
        union { ushort pu[4]; uint2 pv; } pk;
#pragma unroll
        for (int i = 0; i < 4; ++i) {
          float p = fexp2(sv[i]);
          psum += p;
          pk.pu[i] = f2b(p);
        }
        pw[u][nb] = pk.pv;
      }
      // reduce over qd lane-groups (lane bits 4,5)
      psum += __shfl_xor(psum, 16);
      psum += __shfl_xor(psum, 32);
      lrow[u] += psum;
    }
    // O += P V, P direct from registers with permuted key order.
    // Slice s covers keys [32s,32s+32): A = concat(pw[2s], pw[2s+1]);
    // k-slot qd*8+j <-> key (2s+(j>>2))*16 + qd*4 + (j&3), matched on V.
#pragma unroll
    for (int s = 0; s < 2; ++s) {
      union { v8s v; uint2 u2[2]; } a0, a1;
      a0.u2[0] = pw[0][2 * s]; a0.u2[1] = pw[0][2 * s + 1];
      a1.u2[0] = pw[1][2 * s]; a1.u2[1] = pw[1][2 * s + 1];
      __builtin_amdgcn_s_setprio(1);
#pragma unroll
      for (int db = 0; db < 4; ++db) {
        union { v8s v; uint2 u2[2]; } vf;
        vf.u2[0] = Vbuf[rvoff[db] + soff[s][0]];
        vf.u2[1] = Vbuf[rvoff[db] + soff[s][1]];
        oacc[0][db] = __builtin_amdgcn_mfma_f32_16x16x32_bf16(a0.v, vf.v,
                                                              oacc[0][db], 0, 0, 0);
        oacc[1][db] = __builtin_amdgcn_mfma_f32_16x16x32_bf16(a1.v, vf.v,
                                                              oacc[1][db], 0, 0, 0);
      }
      __builtin_amdgcn_s_setprio(0);
    }
  };

  // 2-phase pipeline, 2 barriers/tile:
  //   STAGE(next) ; vmcnt(4) [tile t landed, next stays in flight] ;
  //   barrier(acquire) ; COMPUTE(t) ; barrier(release)
  STAGE(0, 0);
#pragma unroll 1
  for (int it = 0; it < PS / 64; it += 2) {
    STAGE(1, (it + 1) * 64);
    asm volatile("s_waitcnt vmcnt(4)" ::: "memory");
    barrier_fence();
    COMPUTE(0);
    barrier_fence();
    if (it + 2 < PS / 64) {
      STAGE(0, (it + 2) * 64);
      asm volatile("s_waitcnt vmcnt(4)" ::: "memory");
    } else {
      asm volatile("s_waitcnt vmcnt(0)" ::: "memory");
    }
    barrier_fence();
    COMPUTE(1);
    barrier_fence();
  }

  // epilogue: redistribute lrow (indexed by q=ln) to O C-layout (q=qd*4+i)
#pragma unroll
  for (int u = 0; u < 2; ++u) {
#pragma unroll
    for (int i = 0; i < 4; ++i) {
      float inv = 1.f / __shfl(lrow[u], qd * 4 + i);
      int sg = q0 + 32 * w + 16 * u + qd * 4 + i;
      size_t base = (((size_t)b * PS + sg) * PH + h) * PD;
#pragma unroll
      for (int db = 0; db < 4; ++db)
        O[base + db * 16 + ln] = __float2bfloat16(oacc[u][db][i] * inv);
    }
  }
}

// ---------------------------------------------------------------------------
// Legacy fp32-input GEMM (small-ws fallback)
// ---------------------------------------------------------------------------
__device__ __forceinline__ uint2 load4bf(const float* p) {
  const float4 f = *reinterpret_cast<const float4*>(p);
  union { ushort u[4]; uint2 v; } pk;
  pk.u[0] = f2b(f.x); pk.u[1] = f2b(f.y); pk.u[2] = f2b(f.z); pk.u[3] = f2b(f.w);
  return pk.v;
}
__device__ __forceinline__ uint2 load4bf(const __hip_bfloat16* p) {
  return *reinterpret_cast<const uint2*>(p);
}

template <typename AT, int MODE>
__global__ __launch_bounds__(256) void gemm128(
    const AT* __restrict__ A, const float* __restrict__ Bm,
    const float* __restrict__ bias, void* __restrict__ outv, int ldb) {
  __shared__ __hip_bfloat16 As[128][40];
  __shared__ __hip_bfloat16 Bs[128][40];
  const int t = threadIdx.x;
  const int lane = t & 63, w = t >> 6;
  const int ln = lane & 15, qd = lane >> 4;
  const int wm = w >> 1, wn = w & 1;
  const int m0 = blockIdx.y * 128, n0 = blockIdx.x * 128;
  v4f acc[4][4] = {};
  for (int k0 = 0; k0 < PE; k0 += 32) {
    __syncthreads();
#pragma unroll
    for (int i = 0; i < 4; ++i) {
      int p = t + 256 * i;
      int m = p >> 3, kc = p & 7;
      *reinterpret_cast<uint2*>(&As[m][kc * 4]) =
          load4bf(A + (size_t)(m0 + m) * PE + k0 + kc * 4);
    }
#pragma unroll
    for (int i = 0; i < 4; ++i) {
      int p = t + 256 * i;
      int n = p & 127, kc = p >> 7;
      union { ushort u[4]; uint2 v; } pk;
#pragma unroll
      for (int r = 0; r < 4; ++r)
        pk.u[r] = f2b(Bm[(size_t)(k0 + kc * 4 + r) * ldb + n0 + n]);
      *reinterpret_cast<uint2*>(&Bs[n][kc * 4]) = pk.v;
    }
    __syncthreads();
    v8s af[4], bf[4];
#pragma unroll
    for (int mb = 0; mb < 4; ++mb)
      af[mb] = *reinterpret_cast<const v8s*>(&As[wm * 64 + mb * 16 + ln][qd * 8]);
#pragma unroll
    for (int nb = 0; nb < 4; ++nb)
      bf[nb] = *reinterpret_cast<const v8s*>(&Bs[wn * 64 + nb * 16 + ln][qd * 8]);
#pragma unroll
    for (int mb = 0; mb < 4; ++mb)
#pragma unroll
      for (int nb = 0; nb < 4; ++nb)
        acc[mb][nb] = __builtin_amdgcn_mfma_f32_16x16x32_bf16(af[mb], bf[nb],
                                                              acc[mb][nb], 0, 0, 0);
  }
  const int mwb = m0 + wm * 64 + qd * 4;
  const int nwb = n0 + wn * 64 + ln;
  if (MODE == 0) {
    __hip_bfloat16* QKV = (__hip_bfloat16*)outv;
#pragma unroll
    for (int nb = 0; nb < 4; ++nb) {
      int n = nwb + nb * 16;
      float bv = bias[n];
      int which = n >> 10, h = (n >> 6) & 15, d = n & 63;
#pragma unroll
      for (int mb = 0; mb < 4; ++mb) {
        int r0 = mwb + mb * 16;
        int b = r0 >> 11, s0 = r0 & (PS - 1);
        v4f a = acc[mb][nb];
        if (which == 2) {
          union { ushort u[4]; uint2 v; } pk;
#pragma unroll
          for (int i = 0; i < 4; ++i) pk.u[i] = f2b(a[i] + bv);
          size_t idx = (((size_t)(2 * PB + b) * PH + h) * PD + d) * PS + s0;
          *reinterpret_cast<uint2*>(&QKV[idx]) = pk.v;
        } else {
          float sc = (which == 0) ? QSCALE : 1.0f;
          size_t base = (((size_t)(which * PB + b) * PH + h) * PS + s0) * PD + d;
#pragma unroll
          for (int i = 0; i < 4; ++i)
            QKV[base + (size_t)i * PD] = __float2bfloat16((a[i] + bv) * sc);
        }
      }
    }
  } else {
    float* Co = (float*)outv;
#pragma unroll
    for (int nb = 0; nb < 4; ++nb) {
      int n = nwb + nb * 16;
      float bv = bias[n];
#pragma unroll
      for (int mb = 0; mb < 4; ++mb) {
        int r0 = mwb + mb * 16;
        v4f a = acc[mb][nb];
#pragma unroll
        for (int i = 0; i < 4; ++i)
          Co[(size_t)(r0 + i) * PE + n] = a[i] + bv;
      }
    }
  }
}

// ---------------------------------------------------------------------------
extern "C" void kernel_launch(void* const* d_in, const int* in_sizes, int n_in,
                              void* d_out, int out_size, void* d_ws,
                              size_t ws_size, hipStream_t stream) {
  const float* x = (const float*)d_in[0];
  const float* w_qkv = (const float*)d_in[1];
  const float* b_qkv = (const float*)d_in[2];
  const float* w_proj = (const float*)d_in[3];
  const float* b_proj = (const float*)d_in[4];
  float* out = (float*)d_out;

  const size_t xE = (size_t)PB * PS * PE;             // 8,388,608
  const size_t wqE = (size_t)PE * 3 * PE;             // 3,145,728
  const size_t wpE = (size_t)PE * PE;                 // 1,048,576
  const size_t qkvE = (size_t)3 * PB * PH * PS * PD;  // 25,165,824
  const size_t needMain = (xE + wqE + wpE + qkvE) * 2;  // 75,497,472 B

  dim3 blk(256);
  dim3 gq(24, 64), ga(16, 64), gp(8, 64);

  if (ws_size >= needMain) {
    __hip_bfloat16* xb = (__hip_bfloat16*)d_ws;
    __hip_bfloat16* wqkvT = xb + xE;
    __hip_bfloat16* wprojT = wqkvT + wqE;
    __hip_bfloat16* qkv = wprojT + wpE;
    __hip_bfloat16* o = xb;  // xb dead after qkv gemm

    conv_f2b<<<dim3(xE / 1024), blk, 0, stream>>>(x, xb);
    transp_f2b<<<dim3(96, 32), blk, 0, stream>>>(w_qkv, wqkvT, PE, 3 * PE);
    transp_f2b<<<dim3(32, 32), blk, 0, stream>>>(w_proj, wprojT, PE, PE);
    gemm_bt<0><<<gq, blk, 0, stream>>>(xb, wqkvT, b_qkv, qkv);
    attn_mfma7<<<ga, blk, 0, stream>>>(qkv, o);
    gemm_bt<1><<<gp, blk, 0, stream>>>(o, wprojT, b_proj, out);
  } else {
    // legacy small-ws path
    __hip_bfloat16* qkv = (__hip_bfloat16*)d_ws;
    if (ws_size >= (qkvE + xE) * 2) {
      __hip_bfloat16* o = qkv + qkvE;
      gemm128<float, 0><<<gq, blk, 0, stream>>>(x, w_qkv, b_qkv, qkv, 3 * PE);
      attn_mfma7<<<ga, blk, 0, stream>>>(qkv, o);
      gemm128<__hip_bfloat16, 1><<<gp, blk, 0, stream>>>(o, w_proj, b_proj, out, PE);
    } else {
      __hip_bfloat16* o = (__hip_bfloat16*)d_out;
      float* tmp = (float*)d_ws;
      gemm128<float, 0><<<gq, blk, 0, stream>>>(x, w_qkv, b_qkv, qkv, 3 * PE);
      attn_mfma7<<<ga, blk, 0, stream>>>(qkv, o);
      gemm128<__hip_bfloat16, 1><<<gp, blk, 0, stream>>>(o, w_proj, b_proj, tmp, PE);
      hipMemcpyAsync(d_out, tmp, xE * sizeof(float), hipMemcpyDeviceToDevice, stream);
    }
  }
}

// Round 5
// 287.181 us; speedup vs baseline: 1.1691x; 1.0095x over previous
//
#include <hip/hip_runtime.h>
#include <hip/hip_bf16.h>

// B=4, S=2048, E=1024, H=16, D=64
#define PB 4
#define PS 2048
#define PH 16
#define PD 64
#define PE 1024

typedef short v8s __attribute__((ext_vector_type(8)));
typedef float v4f __attribute__((ext_vector_type(4)));

// Q pre-scale: 1/sqrt(D) * log2(e), so softmax exp() becomes exp2()
#define QSCALE 0.18033688f

__device__ __forceinline__ ushort f2b(float f) {
  union { __hip_bfloat16 b; ushort u; } cv;
  cv.b = __float2bfloat16(f);
  return cv.u;
}

#if __has_builtin(__builtin_amdgcn_exp2f)
__device__ __forceinline__ float fexp2(float x) { return __builtin_amdgcn_exp2f(x); }
#else
__device__ __forceinline__ float fexp2(float x) { return exp2f(x); }
#endif

// async 16B global->LDS (direct DMA, no VGPR round trip) — used by GEMMs
__device__ __forceinline__ void cp16(const __hip_bfloat16* g, __hip_bfloat16* l) {
  __builtin_amdgcn_global_load_lds(
      (const __attribute__((address_space(1))) void*)g,
      (__attribute__((address_space(3))) void*)l, 16, 0, 0);
}

// ---------------------------------------------------------------------------
// Prep kernels: fp32 -> bf16 convert / transpose (memory-bound)
// ---------------------------------------------------------------------------
__global__ __launch_bounds__(256) void conv_f2b(const float* __restrict__ S,
                                                __hip_bfloat16* __restrict__ D) {
  int i = blockIdx.x * 256 + threadIdx.x;
  float4 f = reinterpret_cast<const float4*>(S)[i];
  union { ushort u[4]; uint2 v; } pk;
  pk.u[0] = f2b(f.x); pk.u[1] = f2b(f.y); pk.u[2] = f2b(f.z); pk.u[3] = f2b(f.w);
  reinterpret_cast<uint2*>(D)[i] = pk.v;
}

// S [R][C] fp32 -> D [C][R] bf16
__global__ __launch_bounds__(256) void transp_f2b(const float* __restrict__ S,
                                                  __hip_bfloat16* __restrict__ D,
                                                  int R, int C) {
  __shared__ float tile[32][33];
  const int t = threadIdx.x;
  const int tx = t & 31, ty = t >> 5;
  const int r0 = blockIdx.y * 32, c0 = blockIdx.x * 32;
#pragma unroll
  for (int i = 0; i < 4; ++i)
    tile[ty + 8 * i][tx] = S[(size_t)(r0 + ty + 8 * i) * C + c0 + tx];
  __syncthreads();
#pragma unroll
  for (int i = 0; i < 4; ++i)
    D[(size_t)(c0 + ty + 8 * i) * R + r0 + tx] = __float2bfloat16(tile[tx][ty + 8 * i]);
}

// ---------------------------------------------------------------------------
// MFMA GEMM, BK=64, XOR-swizzled LDS, global_load_lds width-16 staging.
// 128x128 tile, 4 waves x (64x64). MODE 0: QKV scatter; MODE 1: proj fp32.
// ---------------------------------------------------------------------------
template <int MODE>
__global__ __launch_bounds__(256) void gemm_bt(
    const __hip_bfloat16* __restrict__ A, const __hip_bfloat16* __restrict__ BT,
    const float* __restrict__ bias, void* __restrict__ outv) {
  __shared__ __hip_bfloat16 As[128 * 64];
  __shared__ __hip_bfloat16 Bs[128 * 64];
  const int t = threadIdx.x;
  const int lane = t & 63, w = t >> 6;
  const int ln = lane & 15, qd = lane >> 4;
  const int wm = w >> 1, wn = w & 1;
  const int m0 = blockIdx.y * 128, n0 = blockIdx.x * 128;
  v4f acc[4][4] = {};

  for (int k0 = 0; k0 < PE; k0 += 64) {
    __syncthreads();
#pragma unroll
    for (int i = 0; i < 4; ++i) {
      int idx = t + 256 * i;           // 0..1023 16B slots
      int r = idx >> 3, cs = idx & 7;  // 8 chunks per 64-elem row
      int cg = cs ^ (r & 7);
      cp16(A + (size_t)(m0 + r) * PE + k0 + cg * 8, As + idx * 8);
      cp16(BT + (size_t)(n0 + r) * PE + k0 + cg * 8, Bs + idx * 8);
    }
    __syncthreads();
#pragma unroll
    for (int kk = 0; kk < 2; ++kk) {
      v8s af[4], bf[4];
#pragma unroll
      for (int mb = 0; mb < 4; ++mb) {
        int ra = wm * 64 + mb * 16 + ln;
        int ca = (kk * 4 + qd) ^ (ra & 7);
        af[mb] = *reinterpret_cast<const v8s*>(As + ra * 64 + ca * 8);
      }
#pragma unroll
      for (int nb = 0; nb < 4; ++nb) {
        int rb = wn * 64 + nb * 16 + ln;
        int cb = (kk * 4 + qd) ^ (rb & 7);
        bf[nb] = *reinterpret_cast<const v8s*>(Bs + rb * 64 + cb * 8);
      }
#pragma unroll
      for (int mb = 0; mb < 4; ++mb)
#pragma unroll
        for (int nb = 0; nb < 4; ++nb)
          acc[mb][nb] = __builtin_amdgcn_mfma_f32_16x16x32_bf16(af[mb], bf[nb],
                                                                acc[mb][nb], 0, 0, 0);
    }
  }

  const int mwb = m0 + wm * 64 + qd * 4;
  const int nwb = n0 + wn * 64 + ln;
  if (MODE == 0) {
    __hip_bfloat16* QKV = (__hip_bfloat16*)outv;
#pragma unroll
    for (int nb = 0; nb < 4; ++nb) {
      int n = nwb + nb * 16;
      float bv = bias[n];
      int which = n >> 10, h = (n >> 6) & 15, d = n & 63;
#pragma unroll
      for (int mb = 0; mb < 4; ++mb) {
        int r0 = mwb + mb * 16;
        int b = r0 >> 11, s0 = r0 & (PS - 1);
        v4f a = acc[mb][nb];
        if (which == 2) {
          union { ushort u[4]; uint2 v; } pk;
#pragma unroll
          for (int i = 0; i < 4; ++i) pk.u[i] = f2b(a[i] + bv);
          size_t idx = (((size_t)(2 * PB + b) * PH + h) * PD + d) * PS + s0;
          *reinterpret_cast<uint2*>(&QKV[idx]) = pk.v;
        } else {
          float sc = (which == 0) ? QSCALE : 1.0f;
          size_t base = (((size_t)(which * PB + b) * PH + h) * PS + s0) * PD + d;
#pragma unroll
          for (int i = 0; i < 4; ++i)
            QKV[base + (size_t)i * PD] = __float2bfloat16((a[i] + bv) * sc);
        }
      }
    }
  } else {
    float* Co = (float*)outv;
#pragma unroll
    for (int nb = 0; nb < 4; ++nb) {
      int n = nwb + nb * 16;
      float bv = bias[n];
#pragma unroll
      for (int mb = 0; mb < 4; ++mb) {
        int r0 = mwb + mb * 16;
        v4f a = acc[mb][nb];
#pragma unroll
        for (int i = 0; i < 4; ++i)
          Co[(size_t)(r0 + i) * PE + n] = a[i] + bv;
      }
    }
  }
}

// ---------------------------------------------------------------------------
// MFMA flash attention v8: register-resident P + T14 async-STAGE split.
// R4 lesson: all global_load_lds-based prefetch variants (v5/v6/v7) tie or
// lose to the simple drain (v4) — the DMA queue cannot decouple from the
// consumer barrier. T14 instead stages via REGISTERS: issue 4 coalesced
// global_load_dwordx4 for tile t+1 BEFORE compute(t); the post-compute
// __syncthreads naturally drains them (HBM latency hidden under ~1000cy of
// MFMA/softmax); then 4 ds_write_b128 (dest-side XOR swizzle, global reads
// stay linear) + one more barrier. Single-buffered 16KB LDS (64-key tiles),
// 2 barriers/tile, no inline asm — compiler inserts all waitcnts correctly
// from the register dependences.
// QKV bf16: Q/K [b,h,s,d], V [b,h,d,s]. O bf16 [b,s,h,d]. Q pre-scaled.
// ---------------------------------------------------------------------------
__global__ __launch_bounds__(256) void attn_mfma8(
    const __hip_bfloat16* __restrict__ QKV, __hip_bfloat16* __restrict__ O) {
  __shared__ __hip_bfloat16 Ks[64 * 64];   // [key][d], XOR-swizzled 16B chunks
  __shared__ __hip_bfloat16 Vts[64 * 64];  // [d][key], XOR-swizzled 16B chunks
  const int t = threadIdx.x;
  const int lane = t & 63, w = t >> 6;
  const int ln = lane & 15, qd = lane >> 4;
  const int b = blockIdx.y >> 4, h = blockIdx.y & 15;
  const int q0 = blockIdx.x * 128;
  const __hip_bfloat16* Qb = QKV + (size_t)(b * PH + h) * PS * PD;
  const __hip_bfloat16* Kb = QKV + (size_t)((PB + b) * PH + h) * PS * PD;
  const __hip_bfloat16* Vb = QKV + (size_t)((2 * PB + b) * PH + h) * PD * PS;

  // Q B-frags: wave w owns q-rows q0+32w .. +31 (two 16-row sub-blocks u)
  v8s qf[2][2];
#pragma unroll
  for (int u = 0; u < 2; ++u) {
    size_t qr = (size_t)(q0 + 32 * w + 16 * u + ln) * PD;
    qf[u][0] = *reinterpret_cast<const v8s*>(Qb + qr + qd * 8);
    qf[u][1] = *reinterpret_cast<const v8s*>(Qb + qr + 32 + qd * 8);
  }
  v4f oacc[2][4] = {};
  float lrow[2] = {0.f, 0.f};

  // kt-invariant LDS read address components
  const int r7 = ln & 7;
  const int c0 = qd ^ r7;  // K 16B-slot base (second read: c0^4)
  const int q1 = qd & 1, qh = qd >> 1;
  int soff[2][2];  // V 8B-slot offsets per k-slice s (uint2 units)
#pragma unroll
  for (int s = 0; s < 2; ++s) {
    int L0 = 4 * s + qh;
    soff[s][0] = (((L0 ^ r7) << 1) | q1);
    soff[s][1] = ((((L0 + 2) ^ r7) << 1) | q1);
  }
  int rvoff[4];  // V row offsets (uint2 units; row = 64 bf16 = 16 uint2)
#pragma unroll
  for (int db = 0; db < 4; ++db) rvoff[db] = (db * 16 + ln) * 16;

  // per-thread staging geometry (kt-invariant): 2 K chunks + 2 V chunks
  // global source is LINEAR (coalesced); LDS dest slot is XOR-swizzled.
  const int sr0 = t >> 3, sc0 = t & 7;            // idx = t
  const int sr1 = (t + 256) >> 3, sc1 = t & 7;    // idx = t+256
  const int dk0 = sr0 * 8 + (sc0 ^ (sr0 & 7));
  const int dk1 = sr1 * 8 + (sc1 ^ (sr1 & 7));

  v8s kreg[2], vreg[2];
  auto LOADR = [&](int kt) {
    kreg[0] = *reinterpret_cast<const v8s*>(Kb + (size_t)(kt + sr0) * PD + sc0 * 8);
    vreg[0] = *reinterpret_cast<const v8s*>(Vb + (size_t)sr0 * PS + kt + sc0 * 8);
    kreg[1] = *reinterpret_cast<const v8s*>(Kb + (size_t)(kt + sr1) * PD + sc1 * 8);
    vreg[1] = *reinterpret_cast<const v8s*>(Vb + (size_t)sr1 * PS + kt + sc1 * 8);
  };
  auto DSWR = [&]() {
    *reinterpret_cast<v8s*>(Ks + dk0 * 8) = kreg[0];
    *reinterpret_cast<v8s*>(Vts + dk0 * 8) = vreg[0];
    *reinterpret_cast<v8s*>(Ks + dk1 * 8) = kreg[1];
    *reinterpret_cast<v8s*>(Vts + dk1 * 8) = vreg[1];
  };

  auto COMPUTE = [&]() {
    const __hip_bfloat16* Kbuf = Ks;
    const uint2* Vbuf = reinterpret_cast<const uint2*>(Vts);
    // S^T = K Q^T per sub-block; exp2; pack P into registers (pw)
    uint2 pw[2][4];
#pragma unroll
    for (int u = 0; u < 2; ++u) {
      float psum = 0.f;
#pragma unroll
      for (int nb = 0; nb < 4; ++nb) {
        const __hip_bfloat16* kr = Kbuf + (nb * 16 + ln) * 64;
        v8s k0 = *reinterpret_cast<const v8s*>(kr + c0 * 8);
        v8s k1 = *reinterpret_cast<const v8s*>(kr + (c0 ^ 4) * 8);
        v4f z = {};
        z = __builtin_amdgcn_mfma_f32_16x16x32_bf16(k0, qf[u][0], z, 0, 0, 0);
        v4f sv = __builtin_amdgcn_mfma_f32_16x16x32_bf16(k1, qf[u][1], z, 0, 0, 0);
        // lane holds keys nb*16+qd*4+i of q = 32w+16u+ln
        union { ushort pu[4]; uint2 pv; } pk;
#pragma unroll
        for (int i = 0; i < 4; ++i) {
          float p = fexp2(sv[i]);
          psum += p;
          pk.pu[i] = f2b(p);
        }
        pw[u][nb] = pk.pv;
      }
      // reduce over qd lane-groups (lane bits 4,5)
      psum += __shfl_xor(psum, 16);
      psum += __shfl_xor(psum, 32);
      lrow[u] += psum;
    }
    // O += P V, P direct from registers with permuted key order.
    // Slice s covers keys [32s,32s+32): A = concat(pw[2s], pw[2s+1]);
    // k-slot qd*8+j <-> key (2s+(j>>2))*16 + qd*4 + (j&3), matched on V.
#pragma unroll
    for (int s = 0; s < 2; ++s) {
      union { v8s v; uint2 u2[2]; } a0, a1;
      a0.u2[0] = pw[0][2 * s]; a0.u2[1] = pw[0][2 * s + 1];
      a1.u2[0] = pw[1][2 * s]; a1.u2[1] = pw[1][2 * s + 1];
      __builtin_amdgcn_s_setprio(1);
#pragma unroll
      for (int db = 0; db < 4; ++db) {
        union { v8s v; uint2 u2[2]; } vf;
        vf.u2[0] = Vbuf[rvoff[db] + soff[s][0]];
        vf.u2[1] = Vbuf[rvoff[db] + soff[s][1]];
        oacc[0][db] = __builtin_amdgcn_mfma_f32_16x16x32_bf16(a0.v, vf.v,
                                                              oacc[0][db], 0, 0, 0);
        oacc[1][db] = __builtin_amdgcn_mfma_f32_16x16x32_bf16(a1.v, vf.v,
                                                              oacc[1][db], 0, 0, 0);
      }
      __builtin_amdgcn_s_setprio(0);
    }
  };

  // T14 async-split loop: load(t+1)->regs BEFORE compute(t); the barrier
  // after compute drains the loads (latency hidden under compute); then
  // regs->LDS + barrier.
  const int NT = PS / 64;
  LOADR(0);
  DSWR();
  __syncthreads();
#pragma unroll 1
  for (int it = 0; it < NT; ++it) {
    if (it + 1 < NT) LOADR((it + 1) * 64);
    COMPUTE();
    __syncthreads();
    if (it + 1 < NT) DSWR();
    __syncthreads();
  }

  // epilogue: redistribute lrow (indexed by q=ln) to O C-layout (q=qd*4+i)
#pragma unroll
  for (int u = 0; u < 2; ++u) {
#pragma unroll
    for (int i = 0; i < 4; ++i) {
      float inv = 1.f / __shfl(lrow[u], qd * 4 + i);
      int sg = q0 + 32 * w + 16 * u + qd * 4 + i;
      size_t base = (((size_t)b * PS + sg) * PH + h) * PD;
#pragma unroll
      for (int db = 0; db < 4; ++db)
        O[base + db * 16 + ln] = __float2bfloat16(oacc[u][db][i] * inv);
    }
  }
}

// ---------------------------------------------------------------------------
// Legacy fp32-input GEMM (small-ws fallback)
// ---------------------------------------------------------------------------
__device__ __forceinline__ uint2 load4bf(const float* p) {
  const float4 f = *reinterpret_cast<const float4*>(p);
  union { ushort u[4]; uint2 v; } pk;
  pk.u[0] = f2b(f.x); pk.u[1] = f2b(f.y); pk.u[2] = f2b(f.z); pk.u[3] = f2b(f.w);
  return pk.v;
}
__device__ __forceinline__ uint2 load4bf(const __hip_bfloat16* p) {
  return *reinterpret_cast<const uint2*>(p);
}

template <typename AT, int MODE>
__global__ __launch_bounds__(256) void gemm128(
    const AT* __restrict__ A, const float* __restrict__ Bm,
    const float* __restrict__ bias, void* __restrict__ outv, int ldb) {
  __shared__ __hip_bfloat16 As[128][40];
  __shared__ __hip_bfloat16 Bs[128][40];
  const int t = threadIdx.x;
  const int lane = t & 63, w = t >> 6;
  const int ln = lane & 15, qd = lane >> 4;
  const int wm = w >> 1, wn = w & 1;
  const int m0 = blockIdx.y * 128, n0 = blockIdx.x * 128;
  v4f acc[4][4] = {};
  for (int k0 = 0; k0 < PE; k0 += 32) {
    __syncthreads();
#pragma unroll
    for (int i = 0; i < 4; ++i) {
      int p = t + 256 * i;
      int m = p >> 3, kc = p & 7;
      *reinterpret_cast<uint2*>(&As[m][kc * 4]) =
          load4bf(A + (size_t)(m0 + m) * PE + k0 + kc * 4);
    }
#pragma unroll
    for (int i = 0; i < 4; ++i) {
      int p = t + 256 * i;
      int n = p & 127, kc = p >> 7;
      union { ushort u[4]; uint2 v; } pk;
#pragma unroll
      for (int r = 0; r < 4; ++r)
        pk.u[r] = f2b(Bm[(size_t)(k0 + kc * 4 + r) * ldb + n0 + n]);
      *reinterpret_cast<uint2*>(&Bs[n][kc * 4]) = pk.v;
    }
    __syncthreads();
    v8s af[4], bf[4];
#pragma unroll
    for (int mb = 0; mb < 4; ++mb)
      af[mb] = *reinterpret_cast<const v8s*>(&As[wm * 64 + mb * 16 + ln][qd * 8]);
#pragma unroll
    for (int nb = 0; nb < 4; ++nb)
      bf[nb] = *reinterpret_cast<const v8s*>(&Bs[wn * 64 + nb * 16 + ln][qd * 8]);
#pragma unroll
    for (int mb = 0; mb < 4; ++mb)
#pragma unroll
      for (int nb = 0; nb < 4; ++nb)
        acc[mb][nb] = __builtin_amdgcn_mfma_f32_16x16x32_bf16(af[mb], bf[nb],
                                                              acc[mb][nb], 0, 0, 0);
  }
  const int mwb = m0 + wm * 64 + qd * 4;
  const int nwb = n0 + wn * 64 + ln;
  if (MODE == 0) {
    __hip_bfloat16* QKV = (__hip_bfloat16*)outv;
#pragma unroll
    for (int nb = 0; nb < 4; ++nb) {
      int n = nwb + nb * 16;
      float bv = bias[n];
      int which = n >> 10, h = (n >> 6) & 15, d = n & 63;
#pragma unroll
      for (int mb = 0; mb < 4; ++mb) {
        int r0 = mwb + mb * 16;
        int b = r0 >> 11, s0 = r0 & (PS - 1);
        v4f a = acc[mb][nb];
        if (which == 2) {
          union { ushort u[4]; uint2 v; } pk;
#pragma unroll
          for (int i = 0; i < 4; ++i) pk.u[i] = f2b(a[i] + bv);
          size_t idx = (((size_t)(2 * PB + b) * PH + h) * PD + d) * PS + s0;
          *reinterpret_cast<uint2*>(&QKV[idx]) = pk.v;
        } else {
          float sc = (which == 0) ? QSCALE : 1.0f;
          size_t base = (((size_t)(which * PB + b) * PH + h) * PS + s0) * PD + d;
#pragma unroll
          for (int i = 0; i < 4; ++i)
            QKV[base + (size_t)i * PD] = __float2bfloat16((a[i] + bv) * sc);
        }
      }
    }
  } else {
    float* Co = (float*)outv;
#pragma unroll
    for (int nb = 0; nb < 4; ++nb) {
      int n = nwb + nb * 16;
      float bv = bias[n];
#pragma unroll
      for (int mb = 0; mb < 4; ++mb) {
        int r0 = mwb + mb * 16;
        v4f a = acc[mb][nb];
#pragma unroll
        for (int i = 0; i < 4; ++i)
          Co[(size_t)(r0 + i) * PE + n] = a[i] + bv;
      }
    }
  }
}

// ---------------------------------------------------------------------------
extern "C" void kernel_launch(void* const* d_in, const int* in_sizes, int n_in,
                              void* d_out, int out_size, void* d_ws,
                              size_t ws_size, hipStream_t stream) {
  const float* x = (const float*)d_in[0];
  const float* w_qkv = (const float*)d_in[1];
  const float* b_qkv = (const float*)d_in[2];
  const float* w_proj = (const float*)d_in[3];
  const float* b_proj = (const float*)d_in[4];
  float* out = (float*)d_out;

  const size_t xE = (size_t)PB * PS * PE;             // 8,388,608
  const size_t wqE = (size_t)PE * 3 * PE;             // 3,145,728
  const size_t wpE = (size_t)PE * PE;                 // 1,048,576
  const size_t qkvE = (size_t)3 * PB * PH * PS * PD;  // 25,165,824
  const size_t needMain = (xE + wqE + wpE + qkvE) * 2;  // 75,497,472 B

  dim3 blk(256);
  dim3 gq(24, 64), ga(16, 64), gp(8, 64);

  if (ws_size >= needMain) {
    __hip_bfloat16* xb = (__hip_bfloat16*)d_ws;
    __hip_bfloat16* wqkvT = xb + xE;
    __hip_bfloat16* wprojT = wqkvT + wqE;
    __hip_bfloat16* qkv = wprojT + wpE;
    __hip_bfloat16* o = xb;  // xb dead after qkv gemm

    conv_f2b<<<dim3(xE / 1024), blk, 0, stream>>>(x, xb);
    transp_f2b<<<dim3(96, 32), blk, 0, stream>>>(w_qkv, wqkvT, PE, 3 * PE);
    transp_f2b<<<dim3(32, 32), blk, 0, stream>>>(w_proj, wprojT, PE, PE);
    gemm_bt<0><<<gq, blk, 0, stream>>>(xb, wqkvT, b_qkv, qkv);
    attn_mfma8<<<ga, blk, 0, stream>>>(qkv, o);
    gemm_bt<1><<<gp, blk, 0, stream>>>(o, wprojT, b_proj, out);
  } else {
    // legacy small-ws path
    __hip_bfloat16* qkv = (__hip_bfloat16*)d_ws;
    if (ws_size >= (qkvE + xE) * 2) {
      __hip_bfloat16* o = qkv + qkvE;
      gemm128<float, 0><<<gq, blk, 0, stream>>>(x, w_qkv, b_qkv, qkv, 3 * PE);
      attn_mfma8<<<ga, blk, 0, stream>>>(qkv, o);
      gemm128<__hip_bfloat16, 1><<<gp, blk, 0, stream>>>(o, w_proj, b_proj, out, PE);
    } else {
      __hip_bfloat16* o = (__hip_bfloat16*)d_out;
      float* tmp = (float*)d_ws;
      gemm128<float, 0><<<gq, blk, 0, stream>>>(x, w_qkv, b_qkv, qkv, 3 * PE);
      attn_mfma8<<<ga, blk, 0, stream>>>(qkv, o);
      gemm128<__hip_bfloat16, 1><<<gp, blk, 0, stream>>>(o, w_proj, b_proj, tmp, PE);
      hipMemcpyAsync(d_out, tmp, xE * sizeof(float), hipMemcpyDeviceToDevice, stream);
    }
  }
}

// Round 7
// 284.931 us; speedup vs baseline: 1.1784x; 1.0079x over previous
//
#include <hip/hip_runtime.h>
#include <hip/hip_bf16.h>

// B=4, S=2048, E=1024, H=16, D=64
#define PB 4
#define PS 2048
#define PH 16
#define PD 64
#define PE 1024

typedef short v8s __attribute__((ext_vector_type(8)));
typedef float v4f __attribute__((ext_vector_type(4)));

// Q pre-scale: 1/sqrt(D) * log2(e), so softmax exp() becomes exp2()
#define QSCALE 0.18033688f

__device__ __forceinline__ ushort f2b(float f) {
  union { __hip_bfloat16 b; ushort u; } cv;
  cv.b = __float2bfloat16(f);
  return cv.u;
}

#if __has_builtin(__builtin_amdgcn_exp2f)
__device__ __forceinline__ float fexp2(float x) { return __builtin_amdgcn_exp2f(x); }
#else
__device__ __forceinline__ float fexp2(float x) { return exp2f(x); }
#endif

// async 16B global->LDS (direct DMA, no VGPR round trip) — used by GEMMs
__device__ __forceinline__ void cp16(const __hip_bfloat16* g, __hip_bfloat16* l) {
  __builtin_amdgcn_global_load_lds(
      (const __attribute__((address_space(1))) void*)g,
      (__attribute__((address_space(3))) void*)l, 16, 0, 0);
}

// XCD-aware bijective block remap (T1): consecutive remapped ids land on the
// SAME XCD in contiguous chunks, so blocks sharing operand panels hit the
// same L2. Requires nwg % 8 == 0 (all our grids: 1024 / 1536 / 512).
__device__ __forceinline__ int xcd_swz(int orig, int nwg) {
  return (orig & 7) * (nwg >> 3) + (orig >> 3);
}

// ---------------------------------------------------------------------------
// Prep kernels: fp32 -> bf16 convert / transpose (memory-bound)
// ---------------------------------------------------------------------------
__global__ __launch_bounds__(256) void conv_f2b(const float* __restrict__ S,
                                                __hip_bfloat16* __restrict__ D) {
  int i = blockIdx.x * 256 + threadIdx.x;
  float4 f = reinterpret_cast<const float4*>(S)[i];
  union { ushort u[4]; uint2 v; } pk;
  pk.u[0] = f2b(f.x); pk.u[1] = f2b(f.y); pk.u[2] = f2b(f.z); pk.u[3] = f2b(f.w);
  reinterpret_cast<uint2*>(D)[i] = pk.v;
}

// S [R][C] fp32 -> D [C][R] bf16
__global__ __launch_bounds__(256) void transp_f2b(const float* __restrict__ S,
                                                  __hip_bfloat16* __restrict__ D,
                                                  int R, int C) {
  __shared__ float tile[32][33];
  const int t = threadIdx.x;
  const int tx = t & 31, ty = t >> 5;
  const int r0 = blockIdx.y * 32, c0 = blockIdx.x * 32;
#pragma unroll
  for (int i = 0; i < 4; ++i)
    tile[ty + 8 * i][tx] = S[(size_t)(r0 + ty + 8 * i) * C + c0 + tx];
  __syncthreads();
#pragma unroll
  for (int i = 0; i < 4; ++i)
    D[(size_t)(c0 + ty + 8 * i) * R + r0 + tx] = __float2bfloat16(tile[tx][ty + 8 * i]);
}

// ---------------------------------------------------------------------------
// MFMA GEMM, BK=64, XOR-swizzled LDS, global_load_lds width-16 staging.
// 128x128 tile, 4 waves x (64x64). MODE 0: QKV scatter; MODE 1: proj fp32.
// XCD-swizzled block ids: consecutive tiles (sharing the A row-panel) land
// on the same XCD's L2.
// ---------------------------------------------------------------------------
template <int MODE>
__global__ __launch_bounds__(256) void gemm_bt(
    const __hip_bfloat16* __restrict__ A, const __hip_bfloat16* __restrict__ BT,
    const float* __restrict__ bias, void* __restrict__ outv) {
  __shared__ __hip_bfloat16 As[128 * 64];
  __shared__ __hip_bfloat16 Bs[128 * 64];
  const int t = threadIdx.x;
  const int lane = t & 63, w = t >> 6;
  const int ln = lane & 15, qd = lane >> 4;
  const int wm = w >> 1, wn = w & 1;
  const int gx = gridDim.x;
  const int swz = xcd_swz(blockIdx.y * gx + blockIdx.x, gx * gridDim.y);
  const int m0 = (swz / gx) * 128, n0 = (swz % gx) * 128;
  v4f acc[4][4] = {};

  for (int k0 = 0; k0 < PE; k0 += 64) {
    __syncthreads();
#pragma unroll
    for (int i = 0; i < 4; ++i) {
      int idx = t + 256 * i;           // 0..1023 16B slots
      int r = idx >> 3, cs = idx & 7;  // 8 chunks per 64-elem row
      int cg = cs ^ (r & 7);
      cp16(A + (size_t)(m0 + r) * PE + k0 + cg * 8, As + idx * 8);
      cp16(BT + (size_t)(n0 + r) * PE + k0 + cg * 8, Bs + idx * 8);
    }
    __syncthreads();
#pragma unroll
    for (int kk = 0; kk < 2; ++kk) {
      v8s af[4], bf[4];
#pragma unroll
      for (int mb = 0; mb < 4; ++mb) {
        int ra = wm * 64 + mb * 16 + ln;
        int ca = (kk * 4 + qd) ^ (ra & 7);
        af[mb] = *reinterpret_cast<const v8s*>(As + ra * 64 + ca * 8);
      }
#pragma unroll
      for (int nb = 0; nb < 4; ++nb) {
        int rb = wn * 64 + nb * 16 + ln;
        int cb = (kk * 4 + qd) ^ (rb & 7);
        bf[nb] = *reinterpret_cast<const v8s*>(Bs + rb * 64 + cb * 8);
      }
#pragma unroll
      for (int mb = 0; mb < 4; ++mb)
#pragma unroll
        for (int nb = 0; nb < 4; ++nb)
          acc[mb][nb] = __builtin_amdgcn_mfma_f32_16x16x32_bf16(af[mb], bf[nb],
                                                                acc[mb][nb], 0, 0, 0);
    }
  }

  const int mwb = m0 + wm * 64 + qd * 4;
  const int nwb = n0 + wn * 64 + ln;
  if (MODE == 0) {
    __hip_bfloat16* QKV = (__hip_bfloat16*)outv;
#pragma unroll
    for (int nb = 0; nb < 4; ++nb) {
      int n = nwb + nb * 16;
      float bv = bias[n];
      int which = n >> 10, h = (n >> 6) & 15, d = n & 63;
#pragma unroll
      for (int mb = 0; mb < 4; ++mb) {
        int r0 = mwb + mb * 16;
        int b = r0 >> 11, s0 = r0 & (PS - 1);
        v4f a = acc[mb][nb];
        if (which == 2) {
          union { ushort u[4]; uint2 v; } pk;
#pragma unroll
          for (int i = 0; i < 4; ++i) pk.u[i] = f2b(a[i] + bv);
          size_t idx = (((size_t)(2 * PB + b) * PH + h) * PD + d) * PS + s0;
          *reinterpret_cast<uint2*>(&QKV[idx]) = pk.v;
        } else {
          float sc = (which == 0) ? QSCALE : 1.0f;
          size_t base = (((size_t)(which * PB + b) * PH + h) * PS + s0) * PD + d;
#pragma unroll
          for (int i = 0; i < 4; ++i)
            QKV[base + (size_t)i * PD] = __float2bfloat16((a[i] + bv) * sc);
        }
      }
    }
  } else {
    float* Co = (float*)outv;
#pragma unroll
    for (int nb = 0; nb < 4; ++nb) {
      int n = nwb + nb * 16;
      float bv = bias[n];
#pragma unroll
      for (int mb = 0; mb < 4; ++mb) {
        int r0 = mwb + mb * 16;
        v4f a = acc[mb][nb];
#pragma unroll
        for (int i = 0; i < 4; ++i)
          Co[(size_t)(r0 + i) * PE + n] = a[i] + bv;
      }
    }
  }
}

// ---------------------------------------------------------------------------
// MFMA flash attention v8 (verified R5 pass, 109us) + XCD swizzle: 8 heads'
// worth of contiguous blocks per XCD so each head's 512KB K/V stays in one
// L2. Register-resident P, T14 reg-staged K/V (load->regs before compute,
// barrier drains, ds_write after), single-buffered 16KB LDS.
// QKV bf16: Q/K [b,h,s,d], V [b,h,d,s]. O bf16 [b,s,h,d]. Q pre-scaled.
// ---------------------------------------------------------------------------
__global__ __launch_bounds__(256) void attn_mfma8(
    const __hip_bfloat16* __restrict__ QKV, __hip_bfloat16* __restrict__ O) {
  __shared__ __hip_bfloat16 Ks[64 * 64];   // [key][d], XOR-swizzled 16B chunks
  __shared__ __hip_bfloat16 Vts[64 * 64];  // [d][key], XOR-swizzled 16B chunks
  const int t = threadIdx.x;
  const int lane = t & 63, w = t >> 6;
  const int ln = lane & 15, qd = lane >> 4;
  const int swz = xcd_swz(blockIdx.y * 16 + blockIdx.x, 16 * 64);
  const int bx = swz & 15, by = swz >> 4;
  const int b = by >> 4, h = by & 15;
  const int q0 = bx * 128;
  const __hip_bfloat16* Qb = QKV + (size_t)(b * PH + h) * PS * PD;
  const __hip_bfloat16* Kb = QKV + (size_t)((PB + b) * PH + h) * PS * PD;
  const __hip_bfloat16* Vb = QKV + (size_t)((2 * PB + b) * PH + h) * PD * PS;

  // Q B-frags: wave w owns q-rows q0+32w .. +31 (two 16-row sub-blocks u)
  v8s qf[2][2];
#pragma unroll
  for (int u = 0; u < 2; ++u) {
    size_t qr = (size_t)(q0 + 32 * w + 16 * u + ln) * PD;
    qf[u][0] = *reinterpret_cast<const v8s*>(Qb + qr + qd * 8);
    qf[u][1] = *reinterpret_cast<const v8s*>(Qb + qr + 32 + qd * 8);
  }
  v4f oacc[2][4] = {};
  float lrow[2] = {0.f, 0.f};

  // kt-invariant LDS read address components
  const int r7 = ln & 7;
  const int c0 = qd ^ r7;  // K 16B-slot base (second read: c0^4)
  const int q1 = qd & 1, qh = qd >> 1;
  int soff[2][2];  // V 8B-slot offsets per k-slice s (uint2 units)
#pragma unroll
  for (int s = 0; s < 2; ++s) {
    int L0 = 4 * s + qh;
    soff[s][0] = (((L0 ^ r7) << 1) | q1);
    soff[s][1] = ((((L0 + 2) ^ r7) << 1) | q1);
  }
  int rvoff[4];  // V row offsets (uint2 units; row = 64 bf16 = 16 uint2)
#pragma unroll
  for (int db = 0; db < 4; ++db) rvoff[db] = (db * 16 + ln) * 16;

  // per-thread staging geometry (kt-invariant): 2 K chunks + 2 V chunks
  // global source is LINEAR (coalesced); LDS dest slot is XOR-swizzled.
  const int sr0 = t >> 3, sc0 = t & 7;            // idx = t
  const int sr1 = (t + 256) >> 3, sc1 = t & 7;    // idx = t+256
  const int dk0 = sr0 * 8 + (sc0 ^ (sr0 & 7));
  const int dk1 = sr1 * 8 + (sc1 ^ (sr1 & 7));

  v8s kreg[2], vreg[2];
  auto LOADR = [&](int kt) {
    kreg[0] = *reinterpret_cast<const v8s*>(Kb + (size_t)(kt + sr0) * PD + sc0 * 8);
    vreg[0] = *reinterpret_cast<const v8s*>(Vb + (size_t)sr0 * PS + kt + sc0 * 8);
    kreg[1] = *reinterpret_cast<const v8s*>(Kb + (size_t)(kt + sr1) * PD + sc1 * 8);
    vreg[1] = *reinterpret_cast<const v8s*>(Vb + (size_t)sr1 * PS + kt + sc1 * 8);
  };
  auto DSWR = [&]() {
    *reinterpret_cast<v8s*>(Ks + dk0 * 8) = kreg[0];
    *reinterpret_cast<v8s*>(Vts + dk0 * 8) = vreg[0];
    *reinterpret_cast<v8s*>(Ks + dk1 * 8) = kreg[1];
    *reinterpret_cast<v8s*>(Vts + dk1 * 8) = vreg[1];
  };

  auto COMPUTE = [&]() {
    const __hip_bfloat16* Kbuf = Ks;
    const uint2* Vbuf = reinterpret_cast<const uint2*>(Vts);
    // S^T = K Q^T per sub-block; exp2; pack P into registers (pw)
    uint2 pw[2][4];
#pragma unroll
    for (int u = 0; u < 2; ++u) {
      float psum = 0.f;
#pragma unroll
      for (int nb = 0; nb < 4; ++nb) {
        const __hip_bfloat16* kr = Kbuf + (nb * 16 + ln) * 64;
        v8s k0 = *reinterpret_cast<const v8s*>(kr + c0 * 8);
        v8s k1 = *reinterpret_cast<const v8s*>(kr + (c0 ^ 4) * 8);
        v4f z = {};
        z = __builtin_amdgcn_mfma_f32_16x16x32_bf16(k0, qf[u][0], z, 0, 0, 0);
        v4f sv = __builtin_amdgcn_mfma_f32_16x16x32_bf16(k1, qf[u][1], z, 0, 0, 0);
        // lane holds keys nb*16+qd*4+i of q = 32w+16u+ln
        union { ushort pu[4]; uint2 pv; } pk;
#pragma unroll
        for (int i = 0; i < 4; ++i) {
          float p = fexp2(sv[i]);
          psum += p;
          pk.pu[i] = f2b(p);
        }
        pw[u][nb] = pk.pv;
      }
      // reduce over qd lane-groups (lane bits 4,5)
      psum += __shfl_xor(psum, 16);
      psum += __shfl_xor(psum, 32);
      lrow[u] += psum;
    }
    // O += P V, P direct from registers with permuted key order.
    // Slice s covers keys [32s,32s+32): A = concat(pw[2s], pw[2s+1]);
    // k-slot qd*8+j <-> key (2s+(j>>2))*16 + qd*4 + (j&3), matched on V.
#pragma unroll
    for (int s = 0; s < 2; ++s) {
      union { v8s v; uint2 u2[2]; } a0, a1;
      a0.u2[0] = pw[0][2 * s]; a0.u2[1] = pw[0][2 * s + 1];
      a1.u2[0] = pw[1][2 * s]; a1.u2[1] = pw[1][2 * s + 1];
      __builtin_amdgcn_s_setprio(1);
#pragma unroll
      for (int db = 0; db < 4; ++db) {
        union { v8s v; uint2 u2[2]; } vf;
        vf.u2[0] = Vbuf[rvoff[db] + soff[s][0]];
        vf.u2[1] = Vbuf[rvoff[db] + soff[s][1]];
        oacc[0][db] = __builtin_amdgcn_mfma_f32_16x16x32_bf16(a0.v, vf.v,
                                                              oacc[0][db], 0, 0, 0);
        oacc[1][db] = __builtin_amdgcn_mfma_f32_16x16x32_bf16(a1.v, vf.v,
                                                              oacc[1][db], 0, 0, 0);
      }
      __builtin_amdgcn_s_setprio(0);
    }
  };

  // T14 async-split loop: load(t+1)->regs BEFORE compute(t); the barrier
  // after compute drains the loads (latency hidden under compute); then
  // regs->LDS + barrier.
  const int NT = PS / 64;
  LOADR(0);
  DSWR();
  __syncthreads();
#pragma unroll 1
  for (int it = 0; it < NT; ++it) {
    if (it + 1 < NT) LOADR((it + 1) * 64);
    COMPUTE();
    __syncthreads();
    if (it + 1 < NT) DSWR();
    __syncthreads();
  }

  // epilogue: redistribute lrow (indexed by q=ln) to O C-layout (q=qd*4+i)
#pragma unroll
  for (int u = 0; u < 2; ++u) {
#pragma unroll
    for (int i = 0; i < 4; ++i) {
      float inv = 1.f / __shfl(lrow[u], qd * 4 + i);
      int sg = q0 + 32 * w + 16 * u + qd * 4 + i;
      size_t base = (((size_t)b * PS + sg) * PH + h) * PD;
#pragma unroll
      for (int db = 0; db < 4; ++db)
        O[base + db * 16 + ln] = __float2bfloat16(oacc[u][db][i] * inv);
    }
  }
}

// ---------------------------------------------------------------------------
// Legacy fp32-input GEMM (small-ws fallback)
// ---------------------------------------------------------------------------
__device__ __forceinline__ uint2 load4bf(const float* p) {
  const float4 f = *reinterpret_cast<const float4*>(p);
  union { ushort u[4]; uint2 v; } pk;
  pk.u[0] = f2b(f.x); pk.u[1] = f2b(f.y); pk.u[2] = f2b(f.z); pk.u[3] = f2b(f.w);
  return pk.v;
}
__device__ __forceinline__ uint2 load4bf(const __hip_bfloat16* p) {
  return *reinterpret_cast<const uint2*>(p);
}

template <typename AT, int MODE>
__global__ __launch_bounds__(256) void gemm128(
    const AT* __restrict__ A, const float* __restrict__ Bm,
    const float* __restrict__ bias, void* __restrict__ outv, int ldb) {
  __shared__ __hip_bfloat16 As[128][40];
  __shared__ __hip_bfloat16 Bs[128][40];
  const int t = threadIdx.x;
  const int lane = t & 63, w = t >> 6;
  const int ln = lane & 15, qd = lane >> 4;
  const int wm = w >> 1, wn = w & 1;
  const int m0 = blockIdx.y * 128, n0 = blockIdx.x * 128;
  v4f acc[4][4] = {};
  for (int k0 = 0; k0 < PE; k0 += 32) {
    __syncthreads();
#pragma unroll
    for (int i = 0; i < 4; ++i) {
      int p = t + 256 * i;
      int m = p >> 3, kc = p & 7;
      *reinterpret_cast<uint2*>(&As[m][kc * 4]) =
          load4bf(A + (size_t)(m0 + m) * PE + k0 + kc * 4);
    }
#pragma unroll
    for (int i = 0; i < 4; ++i) {
      int p = t + 256 * i;
      int n = p & 127, kc = p >> 7;
      union { ushort u[4]; uint2 v; } pk;
#pragma unroll
      for (int r = 0; r < 4; ++r)
        pk.u[r] = f2b(Bm[(size_t)(k0 + kc * 4 + r) * ldb + n0 + n]);
      *reinterpret_cast<uint2*>(&Bs[n][kc * 4]) = pk.v;
    }
    __syncthreads();
    v8s af[4], bf[4];
#pragma unroll
    for (int mb = 0; mb < 4; ++mb)
      af[mb] = *reinterpret_cast<const v8s*>(&As[wm * 64 + mb * 16 + ln][qd * 8]);
#pragma unroll
    for (int nb = 0; nb < 4; ++nb)
      bf[nb] = *reinterpret_cast<const v8s*>(&Bs[wn * 64 + nb * 16 + ln][qd * 8]);
#pragma unroll
    for (int mb = 0; mb < 4; ++mb)
#pragma unroll
      for (int nb = 0; nb < 4; ++nb)
        acc[mb][nb] = __builtin_amdgcn_mfma_f32_16x16x32_bf16(af[mb], bf[nb],
                                                              acc[mb][nb], 0, 0, 0);
  }
  const int mwb = m0 + wm * 64 + qd * 4;
  const int nwb = n0 + wn * 64 + ln;
  if (MODE == 0) {
    __hip_bfloat16* QKV = (__hip_bfloat16*)outv;
#pragma unroll
    for (int nb = 0; nb < 4; ++nb) {
      int n = nwb + nb * 16;
      float bv = bias[n];
      int which = n >> 10, h = (n >> 6) & 15, d = n & 63;
#pragma unroll
      for (int mb = 0; mb < 4; ++mb) {
        int r0 = mwb + mb * 16;
        int b = r0 >> 11, s0 = r0 & (PS - 1);
        v4f a = acc[mb][nb];
        if (which == 2) {
          union { ushort u[4]; uint2 v; } pk;
#pragma unroll
          for (int i = 0; i < 4; ++i) pk.u[i] = f2b(a[i] + bv);
          size_t idx = (((size_t)(2 * PB + b) * PH + h) * PD + d) * PS + s0;
          *reinterpret_cast<uint2*>(&QKV[idx]) = pk.v;
        } else {
          float sc = (which == 0) ? QSCALE : 1.0f;
          size_t base = (((size_t)(which * PB + b) * PH + h) * PS + s0) * PD + d;
#pragma unroll
          for (int i = 0; i < 4; ++i)
            QKV[base + (size_t)i * PD] = __float2bfloat16((a[i] + bv) * sc);
        }
      }
    }
  } else {
    float* Co = (float*)outv;
#pragma unroll
    for (int nb = 0; nb < 4; ++nb) {
      int n = nwb + nb * 16;
      float bv = bias[n];
#pragma unroll
      for (int mb = 0; mb < 4; ++mb) {
        int r0 = mwb + mb * 16;
        v4f a = acc[mb][nb];
#pragma unroll
        for (int i = 0; i < 4; ++i)
          Co[(size_t)(r0 + i) * PE + n] = a[i] + bv;
      }
    }
  }
}

// ---------------------------------------------------------------------------
extern "C" void kernel_launch(void* const* d_in, const int* in_sizes, int n_in,
                              void* d_out, int out_size, void* d_ws,
                              size_t ws_size, hipStream_t stream) {
  const float* x = (const float*)d_in[0];
  const float* w_qkv = (const float*)d_in[1];
  const float* b_qkv = (const float*)d_in[2];
  const float* w_proj = (const float*)d_in[3];
  const float* b_proj = (const float*)d_in[4];
  float* out = (float*)d_out;

  const size_t xE = (size_t)PB * PS * PE;             // 8,388,608
  const size_t wqE = (size_t)PE * 3 * PE;             // 3,145,728
  const size_t wpE = (size_t)PE * PE;                 // 1,048,576
  const size_t qkvE = (size_t)3 * PB * PH * PS * PD;  // 25,165,824
  const size_t needMain = (xE + wqE + wpE + qkvE) * 2;  // 75,497,472 B

  dim3 blk(256);
  dim3 gq(24, 64), ga(16, 64), gp(8, 64);

  if (ws_size >= needMain) {
    __hip_bfloat16* xb = (__hip_bfloat16*)d_ws;
    __hip_bfloat16* wqkvT = xb + xE;
    __hip_bfloat16* wprojT = wqkvT + wqE;
    __hip_bfloat16* qkv = wprojT + wpE;
    __hip_bfloat16* o = xb;  // xb dead after qkv gemm

    conv_f2b<<<dim3(xE / 1024), blk, 0, stream>>>(x, xb);
    transp_f2b<<<dim3(96, 32), blk, 0, stream>>>(w_qkv, wqkvT, PE, 3 * PE);
    transp_f2b<<<dim3(32, 32), blk, 0, stream>>>(w_proj, wprojT, PE, PE);
    gemm_bt<0><<<gq, blk, 0, stream>>>(xb, wqkvT, b_qkv, qkv);
    attn_mfma8<<<ga, blk, 0, stream>>>(qkv, o);
    gemm_bt<1><<<gp, blk, 0, stream>>>(o, wprojT, b_proj, out);
  } else {
    // legacy small-ws path
    __hip_bfloat16* qkv = (__hip_bfloat16*)d_ws;
    if (ws_size >= (qkvE + xE) * 2) {
      __hip_bfloat16* o = qkv + qkvE;
      gemm128<float, 0><<<gq, blk, 0, stream>>>(x, w_qkv, b_qkv, qkv, 3 * PE);
      attn_mfma8<<<ga, blk, 0, stream>>>(qkv, o);
      gemm128<__hip_bfloat16, 1><<<gp, blk, 0, stream>>>(o, w_proj, b_proj, out, PE);
    } else {
      __hip_bfloat16* o = (__hip_bfloat16*)d_out;
      float* tmp = (float*)d_ws;
      gemm128<float, 0><<<gq, blk, 0, stream>>>(x, w_qkv, b_qkv, qkv, 3 * PE);
      attn_mfma8<<<ga, blk, 0, stream>>>(qkv, o);
      gemm128<__hip_bfloat16, 1><<<gp, blk, 0, stream>>>(o, w_proj, b_proj, tmp, PE);
      hipMemcpyAsync(d_out, tmp, xE * sizeof(float), hipMemcpyDeviceToDevice, stream);
    }
  }
}